// Round 3
// baseline (359.560 us; speedup 1.0000x reference)
//
#include <hip/hip_runtime.h>
#include <math.h>

// Problem constants
#define BATCH 8
#define LTOT 4096
#define DEMB 1024
#define NH 16
#define DH 64

// ws layout (float offsets) — ~3.2 MB total
#define WS_S   0                            // S      [B][1024][16]
#define WS_SV  (WS_S + BATCH*DEMB*NH)       // sv     [B][16]
#define WS_WQ  (WS_SV + BATCH*NH)           // wq_nat [B][1024][16] (natural layout)
#define WS_C   (WS_WQ + BATCH*DEMB*NH)      // c      [B][16]
#define WS_V   (WS_C + BATCH*NH)            // V      [B][4096][16]
#define WS_KTV (WS_V + BATCH*LTOT*NH)       // ktv_g  [B][16][64]

#define FMA4(A, s, W) { (A).x += (s)*(W).x; (A).y += (s)*(W).y; (A).z += (s)*(W).z; (A).w += (s)*(W).w; }

// ---------------------------------------------------------------------------
// xw_core v3: y[l][h] = x[l][:] . W[:][h] for 64 rows/block, W is [1024][16].
//   MODE 0: W=Wv, epilogue v=y+bv -> V[b][l][16] + sv[b][h] (atomicAdd).
//   MODE 1: W=wq_nat[b], epilogue z=(y+c)/8 -> sigmoid -> mask -> out[b][h][l].
// 256 thr, grid B*64. Thread = (is=t&15: i-quad-within-slice, rg=t>>4: rows
// rg+16k, k=0..3). x: DIRECT global->reg (each x element used by exactly one
// thread; 4x256B coalesced runs per instr), prefetched one slice ahead.
// W: 4KB/slice in LDS, double-buffered, ONE barrier/slice. Transposed-
// interleaved layout f4idx=(ii*4+hq)*16+is: conflict-free-ish stores AND
// reads (read addr = base + is*16B -> 2-way max), acc stays logical.
// Epilogue: shfl_xor over the 16 is-lanes (bits 0..3), then 5KB LDS
// transpose (stride 20 floats) for coalesced global stores.
// LDS 8.5 KB total; VGPR ~120 -> launch_bounds(256,3) (cap 170, no spill).
// ---------------------------------------------------------------------------
template <int MODE>
__global__ __launch_bounds__(256, 3) void xw_core(
    const float* __restrict__ x, const float* __restrict__ Wg,
    const float* __restrict__ aux,          // MODE0: bv[16]; MODE1: cvec[B][16]
    const int* __restrict__ mask,           // MODE1 only
    float* __restrict__ outp,               // MODE0: V; MODE1: out
    float* __restrict__ sv) {               // MODE0 only
  __shared__ float lds[2048];   // loop: wbuf[2][1024]; epilogue: ylds[64*20] (aliased)
  __shared__ float axl[80];     // MODE1: c[16]; MODE0: svp[4][16]

  const int b  = blockIdx.x >> 6;
  const int l0 = (blockIdx.x & 63) * 64;
  const int t  = threadIdx.x;
  const int is = t & 15;
  const int rg = t >> 4;

  const float4* xg  = (const float4*)(x + ((size_t)(b * LTOT + l0)) * DEMB);
  const float4* Wf4 = (const float4*)((MODE == 0) ? Wg : (Wg + ((size_t)b << 14)));
  float4* wb0 = (float4*)lds;
  float4* wb1 = (float4*)(lds + 1024);

  // stager: thread t holds slice f4 src = is*16 + ii*4 + hq with
  // is=t&15, hq=(t>>4)&3, ii=t>>6; LDS dst = t (conflict-free).
  const int wsrc = (t & 15) * 16 + (t >> 6) * 4 + ((t >> 4) & 3);

  if (MODE == 1 && t < NH) axl[t] = aux[b * NH + t];

  float4 gw  = Wf4[wsrc];
  float4 xa0 = xg[(rg     ) * 256 + is];
  float4 xa1 = xg[(rg + 16) * 256 + is];
  float4 xa2 = xg[(rg + 32) * 256 + is];
  float4 xa3 = xg[(rg + 48) * 256 + is];
  wb0[t] = gw;
  gw = Wf4[256 + wsrc];
  __syncthreads();

  float4 acc[4][4];   // acc[k][q].c = y[row rg+16k][h=q*4+c]
  #pragma unroll
  for (int k = 0; k < 4; ++k)
    #pragma unroll
    for (int q = 0; q < 4; ++q) acc[k][q] = make_float4(0.f, 0.f, 0.f, 0.f);

  for (int s = 0; s < 16; ++s) {
    const float4* wr = (s & 1) ? wb1 : wb0;
    float4 xn0, xn1, xn2, xn3;
    if (s < 15) {   // prefetch next slice's x (hidden under compute)
      xn0 = xg[(rg     ) * 256 + (s + 1) * 16 + is];
      xn1 = xg[(rg + 16) * 256 + (s + 1) * 16 + is];
      xn2 = xg[(rg + 32) * 256 + (s + 1) * 16 + is];
      xn3 = xg[(rg + 48) * 256 + (s + 1) * 16 + is];
    }
    #define CSTEP(II, GET)                                                    \
    {                                                                         \
      const float4 w0 = wr[((II)*4 + 0) * 16 + is];                           \
      const float4 w1 = wr[((II)*4 + 1) * 16 + is];                           \
      const float4 w2 = wr[((II)*4 + 2) * 16 + is];                           \
      const float4 w3 = wr[((II)*4 + 3) * 16 + is];                           \
      const float f0 = GET(xa0), f1 = GET(xa1), f2 = GET(xa2), f3 = GET(xa3); \
      FMA4(acc[0][0], f0, w0) FMA4(acc[0][1], f0, w1)                         \
      FMA4(acc[0][2], f0, w2) FMA4(acc[0][3], f0, w3)                         \
      FMA4(acc[1][0], f1, w0) FMA4(acc[1][1], f1, w1)                         \
      FMA4(acc[1][2], f1, w2) FMA4(acc[1][3], f1, w3)                         \
      FMA4(acc[2][0], f2, w0) FMA4(acc[2][1], f2, w1)                         \
      FMA4(acc[2][2], f2, w2) FMA4(acc[2][3], f2, w3)                         \
      FMA4(acc[3][0], f3, w0) FMA4(acc[3][1], f3, w1)                         \
      FMA4(acc[3][2], f3, w2) FMA4(acc[3][3], f3, w3)                         \
    }
    #define GETX(v) (v).x
    #define GETY(v) (v).y
    #define GETZ(v) (v).z
    #define GETW(v) (v).w
    CSTEP(0, GETX) CSTEP(1, GETY) CSTEP(2, GETZ) CSTEP(3, GETW)
    #undef CSTEP
    if (s < 15) {
      ((s & 1) ? wb0 : wb1)[t] = gw;      // stage slice s+1 into the other buf
      if (s < 14) gw = Wf4[(s + 2) * 256 + wsrc];
      xa0 = xn0; xa1 = xn1; xa2 = xn2; xa3 = xn3;
    }
    __syncthreads();
  }

  // ---- reduce over the 16 is-lanes (lane bits 0..3), register-only
  #pragma unroll
  for (int m = 1; m <= 8; m <<= 1) {
    #pragma unroll
    for (int k = 0; k < 4; ++k)
      #pragma unroll
      for (int q = 0; q < 4; ++q) {
        acc[k][q].x += __shfl_xor(acc[k][q].x, m);
        acc[k][q].y += __shfl_xor(acc[k][q].y, m);
        acc[k][q].z += __shfl_xor(acc[k][q].z, m);
        acc[k][q].w += __shfl_xor(acc[k][q].w, m);
      }
  }
  // writers: one lane per rg-group; ylds[64 rows][20] (pad: f4-stride 5)
  if (is == 0) {
    float4* y4 = (float4*)lds;
    #pragma unroll
    for (int k = 0; k < 4; ++k)
      #pragma unroll
      for (int q = 0; q < 4; ++q)
        y4[(rg + 16 * k) * 5 + q] = acc[k][q];
  }
  __syncthreads();

  if (MODE == 0) {
    // thread (hq=t&3, r=t>>2): V write fully coalesced (t-consecutive f4s)
    const int hq = t & 3, r = t >> 2;
    const float4 bv4 = ((const float4*)aux)[hq];
    float4 v = ((const float4*)lds)[r * 5 + hq];
    v.x += bv4.x; v.y += bv4.y; v.z += bv4.z; v.w += bv4.w;
    ((float4*)outp)[((size_t)(b * LTOT + l0 + r)) * 4 + hq] = v;
    // sv: reduce over rows. lane bits 2..5 = 16 rows within wave.
    float4 p = v;
    #pragma unroll
    for (int m = 4; m <= 32; m <<= 1) {
      p.x += __shfl_xor(p.x, m); p.y += __shfl_xor(p.y, m);
      p.z += __shfl_xor(p.z, m); p.w += __shfl_xor(p.w, m);
    }
    if ((t & 60) == 0) ((float4*)axl)[(t >> 6) * 4 + hq] = p;  // svp[wave][h]
    __syncthreads();
    if (t < NH) {
      float s = axl[t] + axl[16 + t] + axl[32 + t] + axl[48 + t];
      atomicAdd(&sv[b * NH + t], s);
    }
  } else {
    // thread (h=t>>4, lq=t&15): out plane-coalesced (16 f4 = 256B run per h)
    const int h = t >> 4, lq = t & 15;
    const float c = axl[h];
    const int4 mk = ((const int4*)(mask + (size_t)b * LTOT + l0))[lq];
    float4 p;
    float z0 = (lds[(lq * 4 + 0) * 20 + h] + c) * 0.125f;
    float z1 = (lds[(lq * 4 + 1) * 20 + h] + c) * 0.125f;
    float z2 = (lds[(lq * 4 + 2) * 20 + h] + c) * 0.125f;
    float z3 = (lds[(lq * 4 + 3) * 20 + h] + c) * 0.125f;
    p.x = 1.f / (1.f + __expf(-z0));
    p.y = 1.f / (1.f + __expf(-z1));
    p.z = 1.f / (1.f + __expf(-z2));
    p.w = 1.f / (1.f + __expf(-z3));
    if (mk.x == 0) p.x = 0.f;
    if (mk.y == 0) p.y = 0.f;
    if (mk.z == 0) p.z = 0.f;
    if (mk.w == 0) p.w = 0.f;
    ((float4*)outp)[((size_t)(b * NH + h)) * (LTOT / 4) + (l0 >> 2) + lq] = p;
  }
}

// ---------------------------------------------------------------------------
// K1s: S[b][i][h] += sum_l x[b][l][i] * V[b][l][h].  (unchanged from R2 —
// global->FMA outer product, blocks split by i => intra-block partials only)
// ---------------------------------------------------------------------------
__global__ __launch_bounds__(512, 4) void k1s_S(
    const float* __restrict__ x, const float* __restrict__ V,
    float* __restrict__ S) {
  __shared__ float lds[16384];   // part[16 ls][64 i][16 h]

  const int bid = blockIdx.x;
  const int b = bid >> 6;
  const int ib = (bid >> 2) & 15;
  const int lh = bid & 3;
  const int t = threadIdx.x;
  const int iq = t & 7;
  const int hg = (t >> 3) & 3;
  const int ls = t >> 5;

  const float4* xg = (const float4*)(x + ((size_t)(b * LTOT + lh * 1024)) * DEMB);
  const float4* vg = (const float4*)(V + ((size_t)(b * LTOT + lh * 1024)) * NH);
  const int xc0 = ib * 16 + iq, xc1 = xc0 + 8;

  float4 a0[4] = {{0,0,0,0},{0,0,0,0},{0,0,0,0},{0,0,0,0}};
  float4 a1[4] = {{0,0,0,0},{0,0,0,0},{0,0,0,0},{0,0,0,0}};

  #pragma unroll 4
  for (int it = 0; it < 64; ++it) {
    const int l = it * 16 + ls;
    const float4 xq0 = xg[(size_t)l * 256 + xc0];
    const float4 xq1 = xg[(size_t)l * 256 + xc1];
    const float4 vv = vg[l * 4 + hg];
    FMA4(a0[0], xq0.x, vv) FMA4(a0[1], xq0.y, vv)
    FMA4(a0[2], xq0.z, vv) FMA4(a0[3], xq0.w, vv)
    FMA4(a1[0], xq1.x, vv) FMA4(a1[1], xq1.y, vv)
    FMA4(a1[2], xq1.z, vv) FMA4(a1[3], xq1.w, vv)
  }

  {
    float4* p4 = (float4*)lds;
    #pragma unroll
    for (int ii = 0; ii < 4; ++ii) {
      p4[ls * 256 + (iq * 4 + ii) * 4 + hg] = a0[ii];
      p4[ls * 256 + ((iq + 8) * 4 + ii) * 4 + hg] = a1[ii];
    }
  }
  __syncthreads();
  {
    const int il = t & 63, hp = t >> 6;
    float m0 = 0.f, m1 = 0.f;
    #pragma unroll
    for (int k = 0; k < 16; ++k) {
      const float2 u = *(const float2*)&lds[k * 1024 + il * 16 + 2 * hp];
      m0 += u.x; m1 += u.y;
    }
    float* dst = &S[((size_t)b << 14) + (size_t)(ib * 64 + il) * NH + 2 * hp];
    atomicAdd(dst, m0);
    atomicAdd(dst + 1, m1);
  }
}

// ---------------------------------------------------------------------------
// K2a: ktv[b][h][d] = sum_i Wk[i][h*64+d]*S[b][i][h] + bk[h*64+d]*sv[b][h];
//      cvec[b][h] = sum_d bq[h*64+d]*ktv[d].  grid B*16, 256 thr.
// ---------------------------------------------------------------------------
__global__ __launch_bounds__(256) void k2a_ktv(
    const float* __restrict__ Wk, const float* __restrict__ bk,
    const float* __restrict__ bq,
    const float* __restrict__ S, const float* __restrict__ sv,
    float* __restrict__ ktv_g, float* __restrict__ cvec) {
  __shared__ float part[16][64];
  __shared__ float ktv[DH];
  const int b = blockIdx.x >> 4;
  const int h = blockIdx.x & 15;
  const int t = threadIdx.x;
  const float* Sb = S + ((size_t)b << 14);
  const int d4 = t & 15, iseg = t >> 4;
  const float* wkb = Wk + h * DH + d4 * 4;
  float4 kp = {0.f, 0.f, 0.f, 0.f};
  #pragma unroll 4
  for (int i = iseg * 64; i < iseg * 64 + 64; ++i) {
    const float4 w4 = *(const float4*)&wkb[(size_t)i * DEMB];
    const float sS = Sb[i * NH + h];
    FMA4(kp, sS, w4)
  }
  *(float4*)&part[iseg][d4 * 4] = kp;
  __syncthreads();
  if (t < 64) {
    float s2 = 0.f;
    #pragma unroll
    for (int g = 0; g < 16; ++g) s2 += part[g][t];
    s2 += bk[h * DH + t] * sv[b * NH + h];
    ktv[t] = s2;
    ktv_g[(b * NH + h) * DH + t] = s2;
  }
  __syncthreads();
  if (t < 64) {
    float p = bq[h * DH + t] * ktv[t];
    p += __shfl_xor(p, 1);  p += __shfl_xor(p, 2);  p += __shfl_xor(p, 4);
    p += __shfl_xor(p, 8);  p += __shfl_xor(p, 16); p += __shfl_xor(p, 32);
    if (t == 0) cvec[b * NH + h] = p;
  }
}

// ---------------------------------------------------------------------------
// K2b: wq_nat[b][i][h] = sum_d Wq[i][h*64+d]*ktv[b][h][d].  grid B*16, 256 thr.
// kq = ktv concat (1024 floats, LDS). Thread (jq=t&15, rq=t>>4: 4 rows).
// Coalesced Wq reads (4 x 256B runs/instr); shfl_xor over jq; 5KB transpose.
// ---------------------------------------------------------------------------
__global__ __launch_bounds__(256) void k2b_wq(
    const float* __restrict__ Wq, const float* __restrict__ ktv_g,
    float* __restrict__ wq_nat) {
  __shared__ float kq[DEMB];
  __shared__ float ylds[64 * 20];
  const int b = blockIdx.x >> 4;
  const int i0 = (blockIdx.x & 15) * 64;
  const int t = threadIdx.x;
  ((float4*)kq)[t] = ((const float4*)(ktv_g + (size_t)b * DEMB))[t];
  __syncthreads();

  const int jq = t & 15, rq = t >> 4;
  const float4* wq4 = (const float4*)(Wq + (size_t)i0 * DEMB);
  float a[4][16];
  #pragma unroll
  for (int k = 0; k < 4; ++k)
    #pragma unroll
    for (int s = 0; s < 16; ++s) a[k][s] = 0.f;

  #pragma unroll 4
  for (int s = 0; s < 16; ++s) {
    const float4 kv = ((const float4*)kq)[s * 16 + jq];
    #pragma unroll
    for (int k = 0; k < 4; ++k) {
      const float4 w = wq4[(size_t)(rq + 16 * k) * 256 + s * 16 + jq];
      a[k][s] += w.x * kv.x + w.y * kv.y + w.z * kv.z + w.w * kv.w;
    }
  }
  #pragma unroll
  for (int m = 1; m <= 8; m <<= 1)
    #pragma unroll
    for (int k = 0; k < 4; ++k)
      #pragma unroll
      for (int s = 0; s < 16; ++s) a[k][s] += __shfl_xor(a[k][s], m);

  if (jq == 0) {
    #pragma unroll
    for (int k = 0; k < 4; ++k)
      #pragma unroll
      for (int sq = 0; sq < 4; ++sq)
        ((float4*)ylds)[(rq + 16 * k) * 5 + sq] =
            make_float4(a[k][sq * 4], a[k][sq * 4 + 1], a[k][sq * 4 + 2], a[k][sq * 4 + 3]);
  }
  __syncthreads();
  const int hq = t & 3, r = t >> 2;
  ((float4*)wq_nat)[((size_t)b << 12) + (size_t)(i0 + r) * 4 + hq] =
      ((const float4*)ylds)[r * 5 + hq];
}

extern "C" void kernel_launch(void* const* d_in, const int* in_sizes, int n_in,
                              void* d_out, int out_size, void* d_ws, size_t ws_size,
                              hipStream_t stream) {
  const float* x  = (const float*)d_in[0];
  const int* mask = (const int*)d_in[1];
  const float* Wq = (const float*)d_in[2];
  const float* bq = (const float*)d_in[3];
  const float* Wk = (const float*)d_in[4];
  const float* bk = (const float*)d_in[5];
  const float* Wv = (const float*)d_in[6];
  const float* bv = (const float*)d_in[7];
  float* out = (float*)d_out;
  float* ws = (float*)d_ws;

  float* S      = ws + WS_S;
  float* sv     = ws + WS_SV;
  float* wq_nat = ws + WS_WQ;
  float* cvec   = ws + WS_C;
  float* V      = ws + WS_V;
  float* ktv_g  = ws + WS_KTV;

  hipMemsetAsync(sv, 0, BATCH * NH * sizeof(float), stream);
  hipMemsetAsync(S, 0, (size_t)BATCH * DEMB * NH * sizeof(float), stream);

  xw_core<0><<<dim3(BATCH * 64), dim3(256), 0, stream>>>(x, Wv, bv, nullptr, V, sv);
  k1s_S<<<dim3(BATCH * 64), dim3(512), 0, stream>>>(x, V, S);
  k2a_ktv<<<dim3(BATCH * NH), dim3(256), 0, stream>>>(Wk, bk, bq, S, sv, ktv_g, cvec);
  k2b_wq<<<dim3(BATCH * NH), dim3(256), 0, stream>>>(Wq, ktv_g, wq_nat);
  xw_core<1><<<dim3(BATCH * 64), dim3(256), 0, stream>>>(x, wq_nat, cvec, mask, out, nullptr);
}